// Round 1
// baseline (551.239 us; speedup 1.0000x reference)
//
#include <hip/hip_runtime.h>

// Problem geometry (fixed by setup_inputs): n_lig=n_rec=512, d_in=d_out=512.
#define DIN  512
#define DOUT 512
#define NLIG 512
#define NREC 512

typedef float f32x4 __attribute__((ext_vector_type(4)));

// ---------------------------------------------------------------------------
// Phase 1: proj[m,k] = sum_d F[m,d] * W[k, woff+d]  (+ b[k] for the ligand)
// A-rows and W-rows are both contiguous -> "NT" GEMM, LDS-tiled 32x32x32.
// blockIdx.z selects ligand (0) vs receptor (1).
// ---------------------------------------------------------------------------
__global__ __launch_bounds__(256) void proj_kernel(
    const float* __restrict__ lig, const float* __restrict__ rec,
    const float* __restrict__ W,   const float* __restrict__ bias,
    float* __restrict__ lp,        float* __restrict__ rp)
{
    const int sel   = blockIdx.z;
    const float* F  = sel ? rec : lig;
    float*       P  = sel ? rp  : lp;
    const int  woff = sel ? DIN : 0;

    __shared__ float As[32][33];   // +1 pad: conflict-free column reads
    __shared__ float Bs[32][33];

    const int tid  = threadIdx.x;
    const int tx   = tid & 15;          // output-col group (k)
    const int ty   = tid >> 4;          // output-row group (m)
    const int lrow = tid >> 3;          // staging: 0..31
    const int lcol = (tid & 7) * 4;     // staging: 0,4,...,28

    const int m0 = blockIdx.y * 32;
    const int n0 = blockIdx.x * 32;

    float acc00 = 0.f, acc01 = 0.f, acc10 = 0.f, acc11 = 0.f;

    for (int kt = 0; kt < DIN; kt += 32) {
        const f32x4 a = *reinterpret_cast<const f32x4*>(
            &F[(size_t)(m0 + lrow) * DIN + kt + lcol]);
        const f32x4 w = *reinterpret_cast<const f32x4*>(
            &W[(size_t)(n0 + lrow) * (2 * DIN) + woff + kt + lcol]);
        As[lrow][lcol + 0] = a.x; As[lrow][lcol + 1] = a.y;
        As[lrow][lcol + 2] = a.z; As[lrow][lcol + 3] = a.w;
        Bs[lrow][lcol + 0] = w.x; Bs[lrow][lcol + 1] = w.y;
        Bs[lrow][lcol + 2] = w.z; Bs[lrow][lcol + 3] = w.w;
        __syncthreads();
        #pragma unroll
        for (int kk = 0; kk < 32; ++kk) {
            const float a0 = As[ty * 2 + 0][kk];
            const float a1 = As[ty * 2 + 1][kk];
            const float w0 = Bs[tx * 2 + 0][kk];
            const float w1 = Bs[tx * 2 + 1][kk];
            acc00 += a0 * w0; acc01 += a0 * w1;
            acc10 += a1 * w0; acc11 += a1 * w1;
        }
        __syncthreads();
    }

    const int m = m0 + ty * 2;
    const int n = n0 + tx * 2;
    const float b0 = sel ? 0.f : bias[n + 0];
    const float b1 = sel ? 0.f : bias[n + 1];
    P[(size_t)(m + 0) * DOUT + n + 0] = acc00 + b0;
    P[(size_t)(m + 0) * DOUT + n + 1] = acc01 + b1;
    P[(size_t)(m + 1) * DOUT + n + 0] = acc10 + b0;
    P[(size_t)(m + 1) * DOUT + n + 1] = acc11 + b1;
}

// ---------------------------------------------------------------------------
// Phase 2: out[i,j,k] = lp[i,k] + rp[j,k]   (b already folded into lp)
// One block per (i, 16-row j-tile). lp row pinned in registers; rp is
// L2-resident (1 MiB). Nontemporal float4 stores: the 512 MiB output can't
// live in cache and shouldn't evict rp/lp.
// ---------------------------------------------------------------------------
__global__ __launch_bounds__(256) void bcast_kernel(
    const float* __restrict__ lp, const float* __restrict__ rp,
    float* __restrict__ out)
{
    const int i   = blockIdx.y;
    const int jb  = blockIdx.x;
    const int tid = threadIdx.x;
    const int k   = (tid & 127) * 4;  // float4 offset within a 512-row
    const int jj  = tid >> 7;         // 0/1: two j-rows per iteration

    const f32x4 l = *reinterpret_cast<const f32x4*>(&lp[(size_t)i * DOUT + k]);

    #pragma unroll
    for (int jo = 0; jo < 8; ++jo) {
        const int j = jb * 16 + jo * 2 + jj;
        const f32x4 r = *reinterpret_cast<const f32x4*>(&rp[(size_t)j * DOUT + k]);
        const f32x4 v = l + r;
        __builtin_nontemporal_store(
            v, reinterpret_cast<f32x4*>(&out[((size_t)i * NREC + j) * DOUT + k]));
    }
}

extern "C" void kernel_launch(void* const* d_in, const int* in_sizes, int n_in,
                              void* d_out, int out_size, void* d_ws, size_t ws_size,
                              hipStream_t stream) {
    const float* lig  = (const float*)d_in[0];
    const float* rec  = (const float*)d_in[1];
    const float* W    = (const float*)d_in[2];
    const float* bias = (const float*)d_in[3];
    float* out = (float*)d_out;

    float* lp = (float*)d_ws;              // 512*512 f32 = 1 MiB
    float* rp = lp + (size_t)NLIG * DOUT;  // 1 MiB

    dim3 g1(DOUT / 32, NLIG / 32, 2);      // 16 x 16 x 2 = 512 blocks
    proj_kernel<<<g1, 256, 0, stream>>>(lig, rec, W, bias, lp, rp);

    dim3 g2(NREC / 16, NLIG);              // 32 x 512 = 16384 blocks
    bcast_kernel<<<g2, 256, 0, stream>>>(lp, rp, out);
}